// Round 2
// baseline (1989.562 us; speedup 1.0000x reference)
//
#include <hip/hip_runtime.h>

// RNNDoubleStacked: P=4096 particles, F=128 max features (ragged), H=128 hidden.
// Phase A (net1_kernel): per-particle tanh RNN, one block/particle, W_hh1 rows in
//   VGPRs, h double-buffered in LDS (1 barrier/step), early exit at t==len
//   (reference freezes h past len, so stopping is exact).
//   Tail fuses U[p] = h1[p] @ W_ih2^T + b_ih2 + b_hh2 into d_ws (hoists the
//   input projection out of net2's sequential chain).
// Phase B (net2_kernel): single block, 512 threads, strictly sequential 4096-step
//   recurrence h = tanh(U[p] + h @ W_hh2^T). 4 lanes per output row, shfl_xor
//   reduce, double-buffered h (1 barrier/step), U prefetch 1 step ahead.
//   h-reads use a per-q k-rotation so the 4 unique addresses per ds_read_b128
//   land on disjoint bank groups (was a 4-way conflict).

constexpr int PN = 4096;
constexpr int FN = 128;
constexpr int HN = 128;

__device__ __forceinline__ float fast_tanh(float x) {
    // tanh(x) = 1 - 2/(exp(2x)+1); correct +-1 limits via __expf saturation.
    float e = __expf(2.0f * x);
    return 1.0f - 2.0f / (e + 1.0f);
}

__global__ __launch_bounds__(128) void net1_kernel(
    const float* __restrict__ event,
    const int*   __restrict__ lengths,
    const float* __restrict__ W_ih1,
    const float* __restrict__ W_hh1,
    const float* __restrict__ b_ih1,
    const float* __restrict__ b_hh1,
    const float* __restrict__ W_ih2,
    const float* __restrict__ b_ih2,
    const float* __restrict__ b_hh2,
    float* __restrict__ U)
{
    const int p = blockIdx.x;
    const int i = threadIdx.x;                 // output row 0..127

    __shared__ float h[2][HN];                 // double-buffered hidden state
    __shared__ float ev[FN];                   // this particle's input sequence

    ev[i]   = event[p * FN + i];               // coalesced (event is [P,F,1])
    h[0][i] = 0.0f;

    // W_hh1 row i in registers (128 VGPRs) — reused across all steps.
    float w[HN];
    {
        const float4* wrow = reinterpret_cast<const float4*>(W_hh1 + i * HN);
        #pragma unroll
        for (int k = 0; k < HN / 4; ++k) {
            float4 v = wrow[k];
            w[4*k+0] = v.x; w[4*k+1] = v.y; w[4*k+2] = v.z; w[4*k+3] = v.w;
        }
    }
    const float wx   = W_ih1[i];               // W_ih1 is [H,1]
    const float bias = b_ih1[i] + b_hh1[i];
    const int   len  = lengths[p];             // uniform across block, in [1,127)

    __syncthreads();

    // Reference masks updates at t >= len (h frozen) -> just stop at len.
    for (int t = 0; t < len; ++t) {
        const int cur = t & 1;
        const float x = ev[t];                 // LDS broadcast
        float a0 = fmaf(wx, x, bias), a1 = 0.f, a2 = 0.f, a3 = 0.f;
        const float4* h4 = reinterpret_cast<const float4*>(h[cur]);
        #pragma unroll
        for (int k = 0; k < HN / 4; ++k) {
            float4 hv = h4[k];                 // same addr all lanes -> broadcast, conflict-free
            a0 = fmaf(w[4*k+0], hv.x, a0);
            a1 = fmaf(w[4*k+1], hv.y, a1);
            a2 = fmaf(w[4*k+2], hv.z, a2);
            a3 = fmaf(w[4*k+3], hv.w, a3);
        }
        h[cur ^ 1][i] = fast_tanh((a0 + a1) + (a2 + a3));
        __syncthreads();                       // single barrier: dbuf makes W/R safe
    }

    // Tail: U[p][i] = h1 . W_ih2_row_i + b_ih2[i] + b_hh2[i]  (hoisted out of net2)
    {
        const float4* h4 = reinterpret_cast<const float4*>(h[len & 1]);
        const float4* w2 = reinterpret_cast<const float4*>(W_ih2 + i * HN);
        float a0 = b_ih2[i] + b_hh2[i], a1 = 0.f, a2 = 0.f, a3 = 0.f;
        #pragma unroll
        for (int k = 0; k < HN / 4; ++k) {
            float4 hv = h4[k];
            float4 wv = w2[k];
            a0 = fmaf(wv.x, hv.x, a0);
            a1 = fmaf(wv.y, hv.y, a1);
            a2 = fmaf(wv.z, hv.z, a2);
            a3 = fmaf(wv.w, hv.w, a3);
        }
        U[p * HN + i] = (a0 + a1) + (a2 + a3); // coalesced
    }
}

__global__ __launch_bounds__(512) void net2_kernel(
    const float* __restrict__ U,
    const float* __restrict__ W_hh2,
    float* __restrict__ out)
{
    const int tid  = threadIdx.x;
    const int wv   = tid >> 6;                 // wave 0..7
    const int lane = tid & 63;
    const int og   = lane >> 2;                // output group in wave: 0..15
    const int q    = lane & 3;                 // quarter of the dot: 0..3
    const int oi   = (wv << 4) + og;           // output row 0..127

    __shared__ float h[2][HN];                 // double-buffered hidden state

    // Per-q rotation of the k-order: at unrolled step kk every q reads word
    // offset q*32 + 4*((kk+2q)&7); the 4 unique addresses are on disjoint
    // bank groups -> conflict-free (was same-bank 4-way without rotation).
    // W_hh2 words are loaded into the SAME slot kk, so the dot is unchanged.
    float w[32];
    {
        const float4* wbase = reinterpret_cast<const float4*>(W_hh2 + oi * HN + q * 32);
        #pragma unroll
        for (int kk = 0; kk < 8; ++kk) {
            const int idx = (kk + 2 * q) & 7;
            float4 v = wbase[idx];
            w[4*kk+0] = v.x; w[4*kk+1] = v.y; w[4*kk+2] = v.z; w[4*kk+3] = v.w;
        }
    }

    if (tid < HN) h[0][tid] = 0.0f;
    __syncthreads();

    float u_next = U[oi];                      // prefetch row 0

    for (int p = 0; p < PN; ++p) {
        const int cur = p & 1;
        const float u_cur = u_next;
        const int pn = (p + 1 < PN) ? (p + 1) : p;
        u_next = U[pn * HN + oi];              // prefetch next row; hides under matvec

        const float4* h4 = reinterpret_cast<const float4*>(&h[cur][q * 32]);
        float a0 = 0.f, a1 = 0.f, a2 = 0.f, a3 = 0.f;
        #pragma unroll
        for (int kk = 0; kk < 8; ++kk) {
            const int idx = (kk + 2 * q) & 7;
            float4 hv = h4[idx];               // rotated order: conflict-free
            a0 = fmaf(w[4*kk+0], hv.x, a0);
            a1 = fmaf(w[4*kk+1], hv.y, a1);
            a2 = fmaf(w[4*kk+2], hv.z, a2);
            a3 = fmaf(w[4*kk+3], hv.w, a3);
        }
        float s = (a0 + a1) + (a2 + a3);
        s += __shfl_xor(s, 1);                 // combine 4 quarters
        s += __shfl_xor(s, 2);
        if (q == 0) h[cur ^ 1][oi] = fast_tanh(s + u_cur);
        __syncthreads();                       // single barrier: dbuf makes W/R safe
    }

    if (tid < HN) out[tid] = h[PN & 1][tid];   // after p=4095 result is in h[0]
}

extern "C" void kernel_launch(void* const* d_in, const int* in_sizes, int n_in,
                              void* d_out, int out_size, void* d_ws, size_t ws_size,
                              hipStream_t stream)
{
    const float* event   = (const float*)d_in[0];
    const int*   lengths = (const int*)  d_in[1];
    const float* W_ih1   = (const float*)d_in[2];
    const float* W_hh1   = (const float*)d_in[3];
    const float* b_ih1   = (const float*)d_in[4];
    const float* b_hh1   = (const float*)d_in[5];
    const float* W_ih2   = (const float*)d_in[6];
    const float* W_hh2   = (const float*)d_in[7];
    const float* b_ih2   = (const float*)d_in[8];
    const float* b_hh2   = (const float*)d_in[9];
    float* out = (float*)d_out;                // 128 floats
    float* U   = (float*)d_ws;                 // PN*HN floats = 2 MB scratch

    hipLaunchKernelGGL(net1_kernel, dim3(PN), dim3(HN), 0, stream,
                       event, lengths, W_ih1, W_hh1, b_ih1, b_hh1,
                       W_ih2, b_ih2, b_hh2, U);
    hipLaunchKernelGGL(net2_kernel, dim3(1), dim3(512), 0, stream,
                       U, W_hh2, out);
}